// Round 1
// baseline (602.257 us; speedup 1.0000x reference)
//
#include <hip/hip_runtime.h>
#include <hip/hip_bf16.h>

// MixHop: out = [x@w0+b0 | spmm(x@w1+b1) | spmm(spmm(x@w2+b2))]
// N=50000 nodes, E=600000 edges, C=O=128, fp32.

#define NC 128   // feature dim (C == O == 128)
#define BM 64    // GEMM row tile

// ---------------- CSR build ----------------

__global__ void count_kernel(const int* __restrict__ row, int* __restrict__ cnt, int E) {
    int e = blockIdx.x * blockDim.x + threadIdx.x;
    if (e < E) atomicAdd(&cnt[row[e]], 1);
}

// single-block exclusive scan over cnt[0..n) -> rowptr, pos
__global__ __launch_bounds__(1024) void scan_kernel(const int* __restrict__ cnt,
                                                    int* __restrict__ rowptr,
                                                    int* __restrict__ pos, int n) {
    __shared__ int sums[1024];
    int tid = threadIdx.x;
    int chunk = (n + 1023) / 1024;
    int start = tid * chunk;
    int end = start + chunk; if (end > n) end = n;
    int s = 0;
    for (int i = start; i < end; i++) s += cnt[i];
    sums[tid] = s;
    __syncthreads();
    // Hillis-Steele inclusive scan
    for (int off = 1; off < 1024; off <<= 1) {
        int v = sums[tid];
        int add = (tid >= off) ? sums[tid - off] : 0;
        __syncthreads();
        sums[tid] = v + add;
        __syncthreads();
    }
    int base = (tid > 0) ? sums[tid - 1] : 0;
    for (int i = start; i < end; i++) {
        rowptr[i] = base;
        pos[i] = base;
        base += cnt[i];
    }
    if (tid == 1023) rowptr[n] = sums[1023];
}

__global__ void scatter_kernel(const int* __restrict__ row, const int* __restrict__ col,
                               const float* __restrict__ ew, int* __restrict__ pos,
                               int* __restrict__ ccol, float* __restrict__ cw, int E) {
    int e = blockIdx.x * blockDim.x + threadIdx.x;
    if (e < E) {
        int r = row[e];
        int p = atomicAdd(&pos[r], 1);
        ccol[p] = col[e];
        cw[p]   = ew[e];
    }
}

// ---------------- fused 3-hop GEMM ----------------
// grid = (ceil(N/BM), 3); blockIdx.y selects (w,b,dst,ld)

__global__ __launch_bounds__(256) void gemm3_kernel(
    const float* __restrict__ x,
    const float* __restrict__ w0, const float* __restrict__ b0,
    const float* __restrict__ w1, const float* __restrict__ b1,
    const float* __restrict__ w2, const float* __restrict__ b2,
    float* __restrict__ out, float* __restrict__ h1, float* __restrict__ h2, int n)
{
    __shared__ float xs[NC][BM];      // x tile, transposed [k][m]  (32 KB)
    __shared__ float wsb[NC][NC];     // W tile [k][c]              (64 KB)
    __shared__ float bs[NC];

    int hop = blockIdx.y;
    const float* W = (hop == 0) ? w0 : (hop == 1) ? w1 : w2;
    const float* B = (hop == 0) ? b0 : (hop == 1) ? b1 : b2;
    float* Y       = (hop == 0) ? out : (hop == 1) ? h1 : h2;
    int ldy        = (hop == 0) ? 384 : 128;

    int tid = threadIdx.x;
    int m0 = blockIdx.x * BM;

    // stage W (16384 floats) + bias
    {
        const float4* Wv = (const float4*)W;
        float4* wv = (float4*)&wsb[0][0];
        for (int i = tid; i < NC * NC / 4; i += 256) wv[i] = Wv[i];
        if (tid < NC) bs[tid] = B[tid];
    }
    // stage X tile transposed: thread t -> row t/4, col-chunk (t%4)*32
    {
        int r = tid >> 2;
        int c0 = (tid & 3) * 32;
        int gr = m0 + r;
        if (gr < n) {
            const float4* xv = (const float4*)(x + (size_t)gr * NC + c0);
            #pragma unroll
            for (int j = 0; j < 8; j++) {
                float4 v = xv[j];
                int k = c0 + j * 4;
                xs[k + 0][r] = v.x; xs[k + 1][r] = v.y;
                xs[k + 2][r] = v.z; xs[k + 3][r] = v.w;
            }
        } else {
            #pragma unroll
            for (int j = 0; j < 8; j++) {
                int k = c0 + j * 4;
                xs[k + 0][r] = 0.f; xs[k + 1][r] = 0.f;
                xs[k + 2][r] = 0.f; xs[k + 3][r] = 0.f;
            }
        }
    }
    __syncthreads();

    int tx = tid & 31;   // col group: 4 cols
    int ty = tid >> 5;   // row group: 8 rows
    int c0 = tx * 4, r0 = ty * 8;

    float acc[8][4] = {};
    #pragma unroll 4
    for (int k = 0; k < NC; k++) {
        float4 bv = *(const float4*)&wsb[k][c0];
        float4 a0 = *(const float4*)&xs[k][r0];
        float4 a1 = *(const float4*)&xs[k][r0 + 4];
        float a[8] = {a0.x, a0.y, a0.z, a0.w, a1.x, a1.y, a1.z, a1.w};
        #pragma unroll
        for (int i = 0; i < 8; i++) {
            acc[i][0] += a[i] * bv.x;
            acc[i][1] += a[i] * bv.y;
            acc[i][2] += a[i] * bv.z;
            acc[i][3] += a[i] * bv.w;
        }
    }

    float4 bb = *(const float4*)&bs[c0];
    #pragma unroll
    for (int i = 0; i < 8; i++) {
        int gr = m0 + r0 + i;
        if (gr < n) {
            float4 v = {acc[i][0] + bb.x, acc[i][1] + bb.y,
                        acc[i][2] + bb.z, acc[i][3] + bb.w};
            *(float4*)(Y + (size_t)gr * ldy + c0) = v;
        }
    }
}

// ---------------- SpMM: one wave per row ----------------

__global__ __launch_bounds__(256) void spmm_kernel(
    const int* __restrict__ rowptr, const int* __restrict__ ccol,
    const float* __restrict__ cw, const float* __restrict__ v,
    float* __restrict__ out, int ld, int n)
{
    int wid = (blockIdx.x * blockDim.x + threadIdx.x) >> 6;  // row = wave id
    int lane = threadIdx.x & 63;
    if (wid >= n) return;
    int s = rowptr[wid];
    int e = rowptr[wid + 1];
    float2 acc = {0.f, 0.f};
    for (int k = s; k < e; k++) {
        int c = ccol[k];
        float w = cw[k];
        float2 vv = *(const float2*)(v + (size_t)c * NC + lane * 2);
        acc.x += w * vv.x;
        acc.y += w * vv.y;
    }
    float* o = out + (size_t)wid * ld + lane * 2;
    o[0] = acc.x;
    o[1] = acc.y;
}

// ---------------- launch ----------------

extern "C" void kernel_launch(void* const* d_in, const int* in_sizes, int n_in,
                              void* d_out, int out_size, void* d_ws, size_t ws_size,
                              hipStream_t stream) {
    const float* x  = (const float*)d_in[0];
    const float* ew = (const float*)d_in[1];
    const float* w0 = (const float*)d_in[2];
    const float* b0 = (const float*)d_in[3];
    const float* w1 = (const float*)d_in[4];
    const float* b1 = (const float*)d_in[5];
    const float* w2 = (const float*)d_in[6];
    const float* b2 = (const float*)d_in[7];
    const int* row  = (const int*)d_in[8];
    const int* col  = (const int*)d_in[9];
    float* out = (float*)d_out;

    const int N = in_sizes[0] / NC;  // 50000
    const int E = in_sizes[1];       // 600000

    // workspace carve-up (256B aligned)
    char* ws = (char*)d_ws;
    size_t off = 0;
    auto alloc = [&](size_t bytes) {
        void* p = ws + off;
        off += (bytes + 255) & ~(size_t)255;
        return p;
    };
    float* h1    = (float*)alloc((size_t)N * NC * 4);
    float* h2    = (float*)alloc((size_t)N * NC * 4);
    float* t     = (float*)alloc((size_t)N * NC * 4);
    int* cnt     = (int*)alloc((size_t)N * 4);
    int* rowptr  = (int*)alloc((size_t)(N + 1) * 4);
    int* pos     = (int*)alloc((size_t)N * 4);
    int* ccol    = (int*)alloc((size_t)E * 4);
    float* cw    = (float*)alloc((size_t)E * 4);

    // CSR build (graph is re-read every call; no cross-call caching allowed)
    hipMemsetAsync(cnt, 0, (size_t)N * 4, stream);
    count_kernel<<<(E + 255) / 256, 256, 0, stream>>>(row, cnt, E);
    scan_kernel<<<1, 1024, 0, stream>>>(cnt, rowptr, pos, N);
    scatter_kernel<<<(E + 255) / 256, 256, 0, stream>>>(row, col, ew, pos, ccol, cw, E);

    // hop projections: out[:, :128] = x@w0+b0 ; h1 = x@w1+b1 ; h2 = x@w2+b2
    gemm3_kernel<<<dim3((N + BM - 1) / BM, 3), 256, 0, stream>>>(
        x, w0, b0, w1, b1, w2, b2, out, h1, h2, N);

    // x1 = spmm(h1) -> out[:, 128:256]
    int spmm_blocks = (N * 64 + 255) / 256;
    spmm_kernel<<<spmm_blocks, 256, 0, stream>>>(rowptr, ccol, cw, h1, out + 128, 384, N);
    // x2 = spmm(spmm(h2)) -> out[:, 256:384]
    spmm_kernel<<<spmm_blocks, 256, 0, stream>>>(rowptr, ccol, cw, h2, t, 128, N);
    spmm_kernel<<<spmm_blocks, 256, 0, stream>>>(rowptr, ccol, cw, t, out + 256, 384, N);
}

// Round 9
// 472.065 us; speedup vs baseline: 1.2758x; 1.2758x over previous
//
#include <hip/hip_runtime.h>
#include <hip/hip_bf16.h>

// MixHop restructured:
//   Y1 = A@x ; Y2 = A@Y1 ; s1 = A@1 ; s2 = A@s1
//   out = [ x@w0 + 1*b0' | Y1@w1 + s1*b1' | Y2@w2 + s2*b2' ]
// N=50000, E=600000, C=O=128, fp32.
//
// NOTE: cnt/s1 zeroing is done by zero_kernel, NOT hipMemsetAsync — a memset
// inside graph capture was the prime suspect for replay-only corruption
// (poisoned cnt -> negative scatter indices -> OOB writes into harness
// pristine buffers). Kernel dispatches are always ordered in the graph.

#define NC 128
#define BM 64
#define BK 32

// ---------------- init ----------------

__global__ void zero_kernel(int* __restrict__ p, int n) {
    int i = blockIdx.x * blockDim.x + threadIdx.x;
    if (i < n) p[i] = 0;
}

// ---------------- CSR build ----------------

__global__ void count_kernel(const int* __restrict__ row, const float* __restrict__ ew,
                             int* __restrict__ cnt, float* __restrict__ s1, int E) {
    int e = blockIdx.x * blockDim.x + threadIdx.x;
    if (e < E) {
        int r = row[e];
        atomicAdd(&cnt[r], 1);
        atomicAdd(&s1[r], ew[e]);
    }
}

// single-block exclusive scan over cnt[0..n) -> rowptr, pos
__global__ __launch_bounds__(1024) void scan_kernel(const int* __restrict__ cnt,
                                                    int* __restrict__ rowptr,
                                                    int* __restrict__ pos, int n) {
    __shared__ int sums[1024];
    int tid = threadIdx.x;
    int chunk = (n + 1023) / 1024;
    int start = tid * chunk;
    int end = start + chunk; if (end > n) end = n;
    int s = 0;
    for (int i = start; i < end; i++) s += cnt[i];
    sums[tid] = s;
    __syncthreads();
    for (int off = 1; off < 1024; off <<= 1) {
        int v = sums[tid];
        int add = (tid >= off) ? sums[tid - off] : 0;
        __syncthreads();
        sums[tid] = v + add;
        __syncthreads();
    }
    int base = (tid > 0) ? sums[tid - 1] : 0;
    for (int i = start; i < end; i++) {
        rowptr[i] = base;
        pos[i] = base;
        base += cnt[i];
    }
    if (tid == 1023) rowptr[n] = sums[1023];
}

__global__ void scatter_kernel(const int* __restrict__ row, const int* __restrict__ col,
                               const float* __restrict__ ew, int* __restrict__ pos,
                               int* __restrict__ ccol, float* __restrict__ cw, int E) {
    int e = blockIdx.x * blockDim.x + threadIdx.x;
    if (e < E) {
        int r = row[e];
        int p = atomicAdd(&pos[r], 1);
        if (p >= 0 && p < E) {   // OOB guard: never write outside ccol/cw
            ccol[p] = col[e];
            cw[p]   = ew[e];
        }
    }
}

// s2 = A @ s1 (sparse matvec, one thread per row)
__global__ void s2_kernel(const int* __restrict__ rowptr, const int* __restrict__ ccol,
                          const float* __restrict__ cw, const float* __restrict__ s1,
                          float* __restrict__ s2, int n) {
    int i = blockIdx.x * blockDim.x + threadIdx.x;
    if (i >= n) return;
    int s = rowptr[i], e = rowptr[i + 1];
    float acc = 0.f;
    for (int k = s; k < e; k++) acc += cw[k] * s1[ccol[k]];
    s2[i] = acc;
}

// ---------------- SpMM: one wave per row, unroll-4 for MLP ----------------

__global__ __launch_bounds__(256) void spmm_kernel(
    const int* __restrict__ rowptr, const int* __restrict__ ccol,
    const float* __restrict__ cw, const float* __restrict__ v,
    float* __restrict__ out, int n)
{
    int wid = (blockIdx.x * blockDim.x + threadIdx.x) >> 6;
    int lane = threadIdx.x & 63;
    if (wid >= n) return;
    int s = rowptr[wid];
    int e = rowptr[wid + 1];
    float ax = 0.f, ay = 0.f;
    int k = s;
    for (; k + 4 <= e; k += 4) {
        int c0 = ccol[k], c1 = ccol[k + 1], c2 = ccol[k + 2], c3 = ccol[k + 3];
        float w0 = cw[k], w1 = cw[k + 1], w2 = cw[k + 2], w3 = cw[k + 3];
        float2 v0 = *(const float2*)(v + (size_t)c0 * NC + lane * 2);
        float2 v1 = *(const float2*)(v + (size_t)c1 * NC + lane * 2);
        float2 v2 = *(const float2*)(v + (size_t)c2 * NC + lane * 2);
        float2 v3 = *(const float2*)(v + (size_t)c3 * NC + lane * 2);
        ax += w0 * v0.x; ay += w0 * v0.y;
        ax += w1 * v1.x; ay += w1 * v1.y;
        ax += w2 * v2.x; ay += w2 * v2.y;
        ax += w3 * v3.x; ay += w3 * v3.y;
    }
    for (; k < e; k++) {
        int c = ccol[k];
        float w = cw[k];
        float2 vv = *(const float2*)(v + (size_t)c * NC + lane * 2);
        ax += w * vv.x; ay += w * vv.y;
    }
    float2* o = (float2*)(out + (size_t)wid * NC + lane * 2);
    *o = {ax, ay};
}

// ---------------- fused 3-hop GEMM, K-chunked for occupancy ----------------
// grid = (ceil(N/BM), 3). out_h = S_h @ W_h + s_h (x) b_h

__global__ __launch_bounds__(256, 4) void gemm3_kernel(
    const float* __restrict__ x, const float* __restrict__ Y1, const float* __restrict__ Y2,
    const float* __restrict__ w0, const float* __restrict__ b0,
    const float* __restrict__ w1, const float* __restrict__ b1,
    const float* __restrict__ w2, const float* __restrict__ b2,
    const float* __restrict__ s1, const float* __restrict__ s2,
    float* __restrict__ out, int n)
{
    __shared__ float xs[BK][BM];   // 8 KB, transposed [k][m]
    __shared__ float wsb[BK][NC];  // 16 KB, [k][c]

    int hop = blockIdx.y;
    const float* S  = (hop == 0) ? x  : (hop == 1) ? Y1 : Y2;
    const float* W  = (hop == 0) ? w0 : (hop == 1) ? w1 : w2;
    const float* B  = (hop == 0) ? b0 : (hop == 1) ? b1 : b2;
    const float* SV = (hop == 0) ? nullptr : (hop == 1) ? s1 : s2;

    int tid = threadIdx.x;
    int m0 = blockIdx.x * BM;
    int tx = tid & 31, ty = tid >> 5;
    int c0 = tx * 4, r0 = ty * 8;

    // staging coords
    int sr = tid >> 2;            // 0..63 (x row)
    int skk = (tid & 3) * 8;      // 0,8,16,24 (k sub-chunk)
    int gr_s = m0 + sr;
    bool inb = (gr_s < n);

    float acc[8][4] = {};

    for (int kc = 0; kc < NC; kc += BK) {
        if (kc) __syncthreads();
        // stage x tile transposed: 64 rows x 32 k
        float4 a0 = {0,0,0,0}, a1 = {0,0,0,0};
        if (inb) {
            const float4* xv = (const float4*)(S + (size_t)gr_s * NC + kc + skk);
            a0 = xv[0]; a1 = xv[1];
        }
        xs[skk + 0][sr] = a0.x; xs[skk + 1][sr] = a0.y;
        xs[skk + 2][sr] = a0.z; xs[skk + 3][sr] = a0.w;
        xs[skk + 4][sr] = a1.x; xs[skk + 5][sr] = a1.y;
        xs[skk + 6][sr] = a1.z; xs[skk + 7][sr] = a1.w;
        // stage W rows kc..kc+BK (flat 4096 floats = 1024 float4)
        {
            const float4* Wv = (const float4*)(W + (size_t)kc * NC);
            float4* wv = (float4*)&wsb[0][0];
            wv[tid]       = Wv[tid];
            wv[tid + 256] = Wv[tid + 256];
            wv[tid + 512] = Wv[tid + 512];
            wv[tid + 768] = Wv[tid + 768];
        }
        __syncthreads();

        #pragma unroll 8
        for (int k = 0; k < BK; k++) {
            float4 bv = *(const float4*)&wsb[k][c0];
            float4 x0 = *(const float4*)&xs[k][r0];
            float4 x1 = *(const float4*)&xs[k][r0 + 4];
            float a[8] = {x0.x, x0.y, x0.z, x0.w, x1.x, x1.y, x1.z, x1.w};
            #pragma unroll
            for (int i = 0; i < 8; i++) {
                acc[i][0] += a[i] * bv.x;
                acc[i][1] += a[i] * bv.y;
                acc[i][2] += a[i] * bv.z;
                acc[i][3] += a[i] * bv.w;
            }
        }
    }

    float4 bb = *(const float4*)(B + c0);
    #pragma unroll
    for (int i = 0; i < 8; i++) {
        int gr = m0 + r0 + i;
        if (gr < n) {
            float sc = SV ? SV[gr] : 1.0f;
            float4 v = {acc[i][0] + sc * bb.x, acc[i][1] + sc * bb.y,
                        acc[i][2] + sc * bb.z, acc[i][3] + sc * bb.w};
            *(float4*)(out + (size_t)gr * 384 + hop * NC + c0) = v;
        }
    }
}

// ---------------- launch ----------------

extern "C" void kernel_launch(void* const* d_in, const int* in_sizes, int n_in,
                              void* d_out, int out_size, void* d_ws, size_t ws_size,
                              hipStream_t stream) {
    const float* x  = (const float*)d_in[0];
    const float* ew = (const float*)d_in[1];
    const float* w0 = (const float*)d_in[2];
    const float* b0 = (const float*)d_in[3];
    const float* w1 = (const float*)d_in[4];
    const float* b1 = (const float*)d_in[5];
    const float* w2 = (const float*)d_in[6];
    const float* b2 = (const float*)d_in[7];
    const int* row  = (const int*)d_in[8];
    const int* col  = (const int*)d_in[9];
    float* out = (float*)d_out;

    const int N = in_sizes[0] / NC;  // 50000
    const int E = in_sizes[1];       // 600000

    char* ws = (char*)d_ws;
    size_t off = 0;
    auto alloc = [&](size_t bytes) {
        void* p = ws + off;
        off += (bytes + 255) & ~(size_t)255;
        return p;
    };
    float* Y1    = (float*)alloc((size_t)N * NC * 4);
    float* Y2    = (float*)alloc((size_t)N * NC * 4);
    int* cnt     = (int*)alloc((size_t)2 * N * 4);   // cnt[N] then s1[N] (zeroed together)
    float* s1    = (float*)(cnt + N);
    int* rowptr  = (int*)alloc((size_t)(N + 1) * 4);
    int* pos     = (int*)alloc((size_t)N * 4);
    float* s2    = (float*)alloc((size_t)N * 4);
    int* ccol    = (int*)alloc((size_t)E * 4);
    float* cw    = (float*)alloc((size_t)E * 4);

    // CSR build + degree-weight vectors (zeroing via kernel, NOT memset —
    // graph-capture-safe ordering)
    zero_kernel<<<(2 * N + 255) / 256, 256, 0, stream>>>(cnt, 2 * N);
    count_kernel<<<(E + 255) / 256, 256, 0, stream>>>(row, ew, cnt, s1, E);
    scan_kernel<<<1, 1024, 0, stream>>>(cnt, rowptr, pos, N);
    scatter_kernel<<<(E + 255) / 256, 256, 0, stream>>>(row, col, ew, pos, ccol, cw, E);
    s2_kernel<<<(N + 255) / 256, 256, 0, stream>>>(rowptr, ccol, cw, s1, s2, N);

    // Y1 = A@x ; Y2 = A@Y1
    int spmm_blocks = (N * 64 + 255) / 256;
    spmm_kernel<<<spmm_blocks, 256, 0, stream>>>(rowptr, ccol, cw, x, Y1, N);
    spmm_kernel<<<spmm_blocks, 256, 0, stream>>>(rowptr, ccol, cw, Y1, Y2, N);

    // out = [x@w0 + b0 | Y1@w1 + s1*b1 | Y2@w2 + s2*b2]
    gemm3_kernel<<<dim3((N + BM - 1) / BM, 3), 256, 0, stream>>>(
        x, Y1, Y2, w0, b0, w1, b1, w2, b2, s1, s2, out, N);
}

// Round 11
// 367.991 us; speedup vs baseline: 1.6366x; 1.2828x over previous
//
#include <hip/hip_runtime.h>
#include <hip/hip_bf16.h>

// MixHop restructured:
//   Y1 = A@x ; Y2 = A@Y1 ; s1 = A@1 ; s2 = A@s1
//   out = [ x@w0 + 1*b0' | Y1@w1 + s1*b1' | Y2@w2 + s2*b2' ]
// N=50000, E=600000, C=O=128, fp32.
//
// cnt/s1 zeroing via kernel dispatch (NOT hipMemsetAsync) — memset inside
// graph capture caused replay-only corruption (R7). Scan is hierarchical
// (3 kernels) — the single-block scan was 110 µs at 0.14% occupancy (R9).

#define NC 128
#define BM 64
#define BK 32
#define SBLK 256

// ---------------- init ----------------

__global__ void zero_kernel(int* __restrict__ p, int n) {
    int i = blockIdx.x * blockDim.x + threadIdx.x;
    if (i < n) p[i] = 0;
}

// ---------------- CSR build ----------------

__global__ void count_kernel(const int* __restrict__ row, const float* __restrict__ ew,
                             int* __restrict__ cnt, float* __restrict__ s1, int E) {
    int e = blockIdx.x * blockDim.x + threadIdx.x;
    if (e < E) {
        int r = row[e];
        atomicAdd(&cnt[r], 1);
        atomicAdd(&s1[r], ew[e]);
    }
}

// hierarchical exclusive scan, 3 kernels: partial-sums -> base-scan -> final
__global__ __launch_bounds__(SBLK) void scan_partial(const int* __restrict__ cnt,
                                                     int* __restrict__ bsum, int n) {
    int i = blockIdx.x * SBLK + threadIdx.x;
    int v = (i < n) ? cnt[i] : 0;
    #pragma unroll
    for (int off = 32; off; off >>= 1) v += __shfl_down(v, off, 64);
    __shared__ int wsum[4];
    if ((threadIdx.x & 63) == 0) wsum[threadIdx.x >> 6] = v;
    __syncthreads();
    if (threadIdx.x == 0) bsum[blockIdx.x] = wsum[0] + wsum[1] + wsum[2] + wsum[3];
}

__global__ __launch_bounds__(SBLK) void scan_base(const int* __restrict__ bsum,
                                                  int* __restrict__ bbase, int nb) {
    __shared__ int sh[SBLK];
    int tid = threadIdx.x;
    int v = (tid < nb) ? bsum[tid] : 0;
    sh[tid] = v;
    __syncthreads();
    for (int off = 1; off < SBLK; off <<= 1) {
        int add = (tid >= off) ? sh[tid - off] : 0;
        __syncthreads();
        sh[tid] += add;
        __syncthreads();
    }
    if (tid < nb) bbase[tid] = sh[tid] - v;   // exclusive
}

__global__ __launch_bounds__(SBLK) void scan_final(const int* __restrict__ cnt,
                                                   const int* __restrict__ bbase,
                                                   int* __restrict__ rowptr,
                                                   int* __restrict__ pos, int n, int E) {
    int i = blockIdx.x * SBLK + threadIdx.x;
    int tid = threadIdx.x;
    __shared__ int sh[SBLK];
    int v = (i < n) ? cnt[i] : 0;
    sh[tid] = v;
    __syncthreads();
    for (int off = 1; off < SBLK; off <<= 1) {
        int add = (tid >= off) ? sh[tid - off] : 0;
        __syncthreads();
        sh[tid] += add;
        __syncthreads();
    }
    int excl = sh[tid] - v + bbase[blockIdx.x];
    if (i < n) { rowptr[i] = excl; pos[i] = excl; }
    if (i == 0) rowptr[n] = E;
}

__global__ void scatter_kernel(const int* __restrict__ row, const int* __restrict__ col,
                               const float* __restrict__ ew, int* __restrict__ pos,
                               int* __restrict__ ccol, float* __restrict__ cw, int E) {
    int e = blockIdx.x * blockDim.x + threadIdx.x;
    if (e < E) {
        int r = row[e];
        int p = atomicAdd(&pos[r], 1);
        if (p >= 0 && p < E) {   // OOB guard: never write outside ccol/cw
            ccol[p] = col[e];
            cw[p]   = ew[e];
        }
    }
}

// s2 = A @ s1 (sparse matvec, one thread per row)
__global__ void s2_kernel(const int* __restrict__ rowptr, const int* __restrict__ ccol,
                          const float* __restrict__ cw, const float* __restrict__ s1,
                          float* __restrict__ s2, int n) {
    int i = blockIdx.x * blockDim.x + threadIdx.x;
    if (i >= n) return;
    int s = rowptr[i], e = rowptr[i + 1];
    float acc = 0.f;
    for (int k = s; k < e; k++) acc += cw[k] * s1[ccol[k]];
    s2[i] = acc;
}

// ---------------- SpMM: one wave per row, unroll-4 for MLP ----------------

__global__ __launch_bounds__(256) void spmm_kernel(
    const int* __restrict__ rowptr, const int* __restrict__ ccol,
    const float* __restrict__ cw, const float* __restrict__ v,
    float* __restrict__ out, int n)
{
    int wid = (blockIdx.x * blockDim.x + threadIdx.x) >> 6;
    int lane = threadIdx.x & 63;
    if (wid >= n) return;
    int s = rowptr[wid];
    int e = rowptr[wid + 1];
    float ax = 0.f, ay = 0.f;
    int k = s;
    for (; k + 4 <= e; k += 4) {
        int c0 = ccol[k], c1 = ccol[k + 1], c2 = ccol[k + 2], c3 = ccol[k + 3];
        float w0 = cw[k], w1 = cw[k + 1], w2 = cw[k + 2], w3 = cw[k + 3];
        float2 v0 = *(const float2*)(v + (size_t)c0 * NC + lane * 2);
        float2 v1 = *(const float2*)(v + (size_t)c1 * NC + lane * 2);
        float2 v2 = *(const float2*)(v + (size_t)c2 * NC + lane * 2);
        float2 v3 = *(const float2*)(v + (size_t)c3 * NC + lane * 2);
        ax += w0 * v0.x; ay += w0 * v0.y;
        ax += w1 * v1.x; ay += w1 * v1.y;
        ax += w2 * v2.x; ay += w2 * v2.y;
        ax += w3 * v3.x; ay += w3 * v3.y;
    }
    for (; k < e; k++) {
        int c = ccol[k];
        float w = cw[k];
        float2 vv = *(const float2*)(v + (size_t)c * NC + lane * 2);
        ax += w * vv.x; ay += w * vv.y;
    }
    float2* o = (float2*)(out + (size_t)wid * NC + lane * 2);
    *o = {ax, ay};
}

// ---------------- fused 3-hop GEMM, K-chunked for occupancy ----------------
// grid = (ceil(N/BM), 3). out_h = S_h @ W_h + s_h (x) b_h

__global__ __launch_bounds__(256, 4) void gemm3_kernel(
    const float* __restrict__ x, const float* __restrict__ Y1, const float* __restrict__ Y2,
    const float* __restrict__ w0, const float* __restrict__ b0,
    const float* __restrict__ w1, const float* __restrict__ b1,
    const float* __restrict__ w2, const float* __restrict__ b2,
    const float* __restrict__ s1, const float* __restrict__ s2,
    float* __restrict__ out, int n)
{
    __shared__ float xs[BK][BM];   // 8 KB, transposed [k][m]
    __shared__ float wsb[BK][NC];  // 16 KB, [k][c]

    int hop = blockIdx.y;
    const float* S  = (hop == 0) ? x  : (hop == 1) ? Y1 : Y2;
    const float* W  = (hop == 0) ? w0 : (hop == 1) ? w1 : w2;
    const float* B  = (hop == 0) ? b0 : (hop == 1) ? b1 : b2;
    const float* SV = (hop == 0) ? nullptr : (hop == 1) ? s1 : s2;

    int tid = threadIdx.x;
    int m0 = blockIdx.x * BM;
    int tx = tid & 31, ty = tid >> 5;
    int c0 = tx * 4, r0 = ty * 8;

    // staging coords
    int sr = tid >> 2;            // 0..63 (x row)
    int skk = (tid & 3) * 8;      // 0,8,16,24 (k sub-chunk)
    int gr_s = m0 + sr;
    bool inb = (gr_s < n);

    float acc[8][4] = {};

    for (int kc = 0; kc < NC; kc += BK) {
        if (kc) __syncthreads();
        // stage x tile transposed: 64 rows x 32 k
        float4 a0 = {0,0,0,0}, a1 = {0,0,0,0};
        if (inb) {
            const float4* xv = (const float4*)(S + (size_t)gr_s * NC + kc + skk);
            a0 = xv[0]; a1 = xv[1];
        }
        xs[skk + 0][sr] = a0.x; xs[skk + 1][sr] = a0.y;
        xs[skk + 2][sr] = a0.z; xs[skk + 3][sr] = a0.w;
        xs[skk + 4][sr] = a1.x; xs[skk + 5][sr] = a1.y;
        xs[skk + 6][sr] = a1.z; xs[skk + 7][sr] = a1.w;
        // stage W rows kc..kc+BK (flat 4096 floats = 1024 float4)
        {
            const float4* Wv = (const float4*)(W + (size_t)kc * NC);
            float4* wv = (float4*)&wsb[0][0];
            wv[tid]       = Wv[tid];
            wv[tid + 256] = Wv[tid + 256];
            wv[tid + 512] = Wv[tid + 512];
            wv[tid + 768] = Wv[tid + 768];
        }
        __syncthreads();

        #pragma unroll 8
        for (int k = 0; k < BK; k++) {
            float4 bv = *(const float4*)&wsb[k][c0];
            float4 x0 = *(const float4*)&xs[k][r0];
            float4 x1 = *(const float4*)&xs[k][r0 + 4];
            float a[8] = {x0.x, x0.y, x0.z, x0.w, x1.x, x1.y, x1.z, x1.w};
            #pragma unroll
            for (int i = 0; i < 8; i++) {
                acc[i][0] += a[i] * bv.x;
                acc[i][1] += a[i] * bv.y;
                acc[i][2] += a[i] * bv.z;
                acc[i][3] += a[i] * bv.w;
            }
        }
    }

    float4 bb = *(const float4*)(B + c0);
    #pragma unroll
    for (int i = 0; i < 8; i++) {
        int gr = m0 + r0 + i;
        if (gr < n) {
            float sc = SV ? SV[gr] : 1.0f;
            float4 v = {acc[i][0] + sc * bb.x, acc[i][1] + sc * bb.y,
                        acc[i][2] + sc * bb.z, acc[i][3] + sc * bb.w};
            *(float4*)(out + (size_t)gr * 384 + hop * NC + c0) = v;
        }
    }
}

// ---------------- launch ----------------

extern "C" void kernel_launch(void* const* d_in, const int* in_sizes, int n_in,
                              void* d_out, int out_size, void* d_ws, size_t ws_size,
                              hipStream_t stream) {
    const float* x  = (const float*)d_in[0];
    const float* ew = (const float*)d_in[1];
    const float* w0 = (const float*)d_in[2];
    const float* b0 = (const float*)d_in[3];
    const float* w1 = (const float*)d_in[4];
    const float* b1 = (const float*)d_in[5];
    const float* w2 = (const float*)d_in[6];
    const float* b2 = (const float*)d_in[7];
    const int* row  = (const int*)d_in[8];
    const int* col  = (const int*)d_in[9];
    float* out = (float*)d_out;

    const int N = in_sizes[0] / NC;  // 50000
    const int E = in_sizes[1];       // 600000

    char* ws = (char*)d_ws;
    size_t off = 0;
    auto alloc = [&](size_t bytes) {
        void* p = ws + off;
        off += (bytes + 255) & ~(size_t)255;
        return p;
    };
    float* Y1    = (float*)alloc((size_t)N * NC * 4);
    float* Y2    = (float*)alloc((size_t)N * NC * 4);
    int* cnt     = (int*)alloc((size_t)2 * N * 4);   // cnt[N] then s1[N] (zeroed together)
    float* s1    = (float*)(cnt + N);
    int* rowptr  = (int*)alloc((size_t)(N + 1) * 4);
    int* pos     = (int*)alloc((size_t)N * 4);
    float* s2    = (float*)alloc((size_t)N * 4);
    int* ccol    = (int*)alloc((size_t)E * 4);
    float* cw    = (float*)alloc((size_t)E * 4);

    int nb = (N + SBLK - 1) / SBLK;                  // 196 scan blocks
    int* bsum  = (int*)alloc((size_t)nb * 4);
    int* bbase = (int*)alloc((size_t)nb * 4);

    // CSR build + degree-weight vectors (zeroing via kernel — graph-safe)
    zero_kernel<<<(2 * N + 255) / 256, 256, 0, stream>>>(cnt, 2 * N);
    count_kernel<<<(E + 255) / 256, 256, 0, stream>>>(row, ew, cnt, s1, E);
    scan_partial<<<nb, SBLK, 0, stream>>>(cnt, bsum, N);
    scan_base<<<1, SBLK, 0, stream>>>(bsum, bbase, nb);
    scan_final<<<nb, SBLK, 0, stream>>>(cnt, bbase, rowptr, pos, N, E);
    scatter_kernel<<<(E + 255) / 256, 256, 0, stream>>>(row, col, ew, pos, ccol, cw, E);
    s2_kernel<<<(N + 255) / 256, 256, 0, stream>>>(rowptr, ccol, cw, s1, s2, N);

    // Y1 = A@x ; Y2 = A@Y1
    int spmm_blocks = (N * 64 + 255) / 256;
    spmm_kernel<<<spmm_blocks, 256, 0, stream>>>(rowptr, ccol, cw, x, Y1, N);
    spmm_kernel<<<spmm_blocks, 256, 0, stream>>>(rowptr, ccol, cw, Y1, Y2, N);

    // out = [x@w0 + b0 | Y1@w1 + s1*b1 | Y2@w2 + s2*b2]
    gemm3_kernel<<<dim3((N + BM - 1) / BM, 3), 256, 0, stream>>>(
        x, Y1, Y2, w0, b0, w1, b1, w2, b2, s1, s2, out, N);
}

// Round 14
// 306.856 us; speedup vs baseline: 1.9627x; 1.1992x over previous
//
#include <hip/hip_runtime.h>
#include <hip/hip_bf16.h>

// MixHop restructured + bf16/MFMA dense path:
//   xb = bf16(x); Y1b = A@xb ; Y2b = A@Y1b ; s1 = rowsum(A) (in spmm1); s2 = A@s1
//   out = [ xb@w0 + b0 | Y1b@w1 + s1*b1 | Y2b@w2 + s2*b2 ]   (MFMA bf16, fp32 acc)
// N=50000, E=600000, C=O=128, fp32 in/out. Threshold 0.655; bf16 err ~0.1-0.3.
//
// History: R7 memset-in-capture corruption -> zero via kernel. R9 single-block
// scan 110us -> hierarchical. R11 gemm3 fp32 VALU-bound 81us, MfmaUtil=0 ->
// this round: bf16 MFMA gemm + bf16 spmm gathers.

#define NC 128
#define SBLK 256

typedef unsigned short ushort_t;
typedef unsigned int uint_t;
typedef __attribute__((ext_vector_type(8))) short short8v;   // 8 bf16 = 4 VGPR
typedef __attribute__((ext_vector_type(4))) float float4v;   // mfma acc

__device__ __forceinline__ ushort_t f2bf(float f) {          // RNE fp32->bf16
    uint_t u = __float_as_uint(f);
    return (ushort_t)((u + 0x7fffu + ((u >> 16) & 1u)) >> 16);
}
__device__ __forceinline__ float bf2f(ushort_t s) {
    return __uint_as_float(((uint_t)s) << 16);
}

// ---------------- init / converts ----------------

__global__ void zero_kernel(int* __restrict__ p, int n) {
    int i = blockIdx.x * blockDim.x + threadIdx.x;
    if (i < n) p[i] = 0;
}

// x (fp32, n*128) -> xb (bf16), 8 elems/thread
__global__ void convert_x(const float* __restrict__ x, ushort_t* __restrict__ xb, int total8) {
    int i = blockIdx.x * blockDim.x + threadIdx.x;
    if (i >= total8) return;
    const float4* xp = (const float4*)(x + (size_t)i * 8);
    float4 a = xp[0], b = xp[1];
    uint_t p0 = (uint_t)f2bf(a.x) | ((uint_t)f2bf(a.y) << 16);
    uint_t p1 = (uint_t)f2bf(a.z) | ((uint_t)f2bf(a.w) << 16);
    uint_t p2 = (uint_t)f2bf(b.x) | ((uint_t)f2bf(b.y) << 16);
    uint_t p3 = (uint_t)f2bf(b.z) | ((uint_t)f2bf(b.w) << 16);
    uint4 v = {p0, p1, p2, p3};
    *(uint4*)(xb + (size_t)i * 8) = v;
}

// wbT[h][n][k] = bf16(w_h[k][n])  (3 x 128 x 128)
__global__ void convert_w(const float* __restrict__ w0, const float* __restrict__ w1,
                          const float* __restrict__ w2, ushort_t* __restrict__ wbT) {
    int t = blockIdx.x * blockDim.x + threadIdx.x;
    if (t >= 3 * NC * NC) return;
    int h = t / (NC * NC);
    int rem = t - h * NC * NC;
    int nrow = rem / NC;
    int k = rem - nrow * NC;
    const float* W = (h == 0) ? w0 : (h == 1) ? w1 : w2;
    wbT[t] = f2bf(W[(size_t)k * NC + nrow]);
}

// ---------------- CSR build ----------------

__global__ void count_kernel(const int* __restrict__ row, int* __restrict__ cnt, int E) {
    int e = blockIdx.x * blockDim.x + threadIdx.x;
    if (e < E) atomicAdd(&cnt[row[e]], 1);
}

__global__ __launch_bounds__(SBLK) void scan_partial(const int* __restrict__ cnt,
                                                     int* __restrict__ bsum, int n) {
    int i = blockIdx.x * SBLK + threadIdx.x;
    int v = (i < n) ? cnt[i] : 0;
    #pragma unroll
    for (int off = 32; off; off >>= 1) v += __shfl_down(v, off, 64);
    __shared__ int wsum[4];
    if ((threadIdx.x & 63) == 0) wsum[threadIdx.x >> 6] = v;
    __syncthreads();
    if (threadIdx.x == 0) bsum[blockIdx.x] = wsum[0] + wsum[1] + wsum[2] + wsum[3];
}

__global__ __launch_bounds__(SBLK) void scan_base(const int* __restrict__ bsum,
                                                  int* __restrict__ bbase, int nb) {
    __shared__ int sh[SBLK];
    int tid = threadIdx.x;
    int v = (tid < nb) ? bsum[tid] : 0;
    sh[tid] = v;
    __syncthreads();
    for (int off = 1; off < SBLK; off <<= 1) {
        int add = (tid >= off) ? sh[tid - off] : 0;
        __syncthreads();
        sh[tid] += add;
        __syncthreads();
    }
    if (tid < nb) bbase[tid] = sh[tid] - v;   // exclusive
}

__global__ __launch_bounds__(SBLK) void scan_final(const int* __restrict__ cnt,
                                                   const int* __restrict__ bbase,
                                                   int* __restrict__ rowptr,
                                                   int* __restrict__ pos, int n, int E) {
    int i = blockIdx.x * SBLK + threadIdx.x;
    int tid = threadIdx.x;
    __shared__ int sh[SBLK];
    int v = (i < n) ? cnt[i] : 0;
    sh[tid] = v;
    __syncthreads();
    for (int off = 1; off < SBLK; off <<= 1) {
        int add = (tid >= off) ? sh[tid - off] : 0;
        __syncthreads();
        sh[tid] += add;
        __syncthreads();
    }
    int excl = sh[tid] - v + bbase[blockIdx.x];
    if (i < n) { rowptr[i] = excl; pos[i] = excl; }
    if (i == 0) rowptr[n] = E;
}

__global__ void scatter_kernel(const int* __restrict__ row, const int* __restrict__ col,
                               const float* __restrict__ ew, int* __restrict__ pos,
                               int* __restrict__ ccol, float* __restrict__ cw, int E) {
    int e = blockIdx.x * blockDim.x + threadIdx.x;
    if (e < E) {
        int r = row[e];
        int p = atomicAdd(&pos[r], 1);
        if (p >= 0 && p < E) {   // OOB guard
            ccol[p] = col[e];
            cw[p]   = ew[e];
        }
    }
}

// s2 = A @ s1 (one thread per row)
__global__ void s2_kernel(const int* __restrict__ rowptr, const int* __restrict__ ccol,
                          const float* __restrict__ cw, const float* __restrict__ s1,
                          float* __restrict__ s2, int n) {
    int i = blockIdx.x * blockDim.x + threadIdx.x;
    if (i >= n) return;
    int s = rowptr[i], e = rowptr[i + 1];
    float acc = 0.f;
    for (int k = s; k < e; k++) acc += cw[k] * s1[ccol[k]];
    s2[i] = acc;
}

// ---------------- SpMM bf16: one wave per row; lane = 2 cols ----------------
// optionally emits s1[row] = sum of edge weights (spmm1 only)

__global__ __launch_bounds__(256) void spmm_bf16(
    const int* __restrict__ rowptr, const int* __restrict__ ccol,
    const float* __restrict__ cw, const ushort_t* __restrict__ v,
    ushort_t* __restrict__ outb, float* __restrict__ s1_out, int n)
{
    int wid = (blockIdx.x * blockDim.x + threadIdx.x) >> 6;
    int lane = threadIdx.x & 63;
    if (wid >= n) return;
    int s = rowptr[wid];
    int e = rowptr[wid + 1];
    float ax = 0.f, ay = 0.f, sw = 0.f;
    int k = s;
    for (; k + 4 <= e; k += 4) {
        int c0 = ccol[k], c1 = ccol[k + 1], c2 = ccol[k + 2], c3 = ccol[k + 3];
        float w0 = cw[k], w1 = cw[k + 1], w2 = cw[k + 2], w3 = cw[k + 3];
        uint_t g0 = *(const uint_t*)(v + (size_t)c0 * NC + lane * 2);
        uint_t g1 = *(const uint_t*)(v + (size_t)c1 * NC + lane * 2);
        uint_t g2 = *(const uint_t*)(v + (size_t)c2 * NC + lane * 2);
        uint_t g3 = *(const uint_t*)(v + (size_t)c3 * NC + lane * 2);
        ax += w0 * bf2f(g0 & 0xffff); ay += w0 * bf2f(g0 >> 16);
        ax += w1 * bf2f(g1 & 0xffff); ay += w1 * bf2f(g1 >> 16);
        ax += w2 * bf2f(g2 & 0xffff); ay += w2 * bf2f(g2 >> 16);
        ax += w3 * bf2f(g3 & 0xffff); ay += w3 * bf2f(g3 >> 16);
        sw += w0 + w1 + w2 + w3;
    }
    for (; k < e; k++) {
        int c = ccol[k];
        float w = cw[k];
        uint_t g = *(const uint_t*)(v + (size_t)c * NC + lane * 2);
        ax += w * bf2f(g & 0xffff); ay += w * bf2f(g >> 16);
        sw += w;
    }
    uint_t packed = (uint_t)f2bf(ax) | ((uint_t)f2bf(ay) << 16);
    *(uint_t*)(outb + (size_t)wid * NC + lane * 2) = packed;
    if (s1_out && lane == 0) s1_out[wid] = sw;
}

// ---------------- MFMA bf16 GEMM: out_h = S_h @ W_h + sv_h (x) b_h ----------
// grid = (ceil(N/64), 3), 256 thr = 4 waves. Wave w: rows [w*16, w*16+16).
// mfma_f32_16x16x32_bf16; C/D: col=lane&15, row=(lane>>4)*4+j [m89 verified].
// A: row=lane&15, k=(lane>>4)*8+j ; B: col=lane&15 (= wbT row), same k.

__global__ __launch_bounds__(256) void gemm3_mfma(
    const ushort_t* __restrict__ xb, const ushort_t* __restrict__ Y1b,
    const ushort_t* __restrict__ Y2b, const ushort_t* __restrict__ wbT,
    const float* __restrict__ b0, const float* __restrict__ b1, const float* __restrict__ b2,
    const float* __restrict__ s1, const float* __restrict__ s2,
    float* __restrict__ out, int n)
{
    __shared__ ushort_t ss[64][NC + 8];   // +8 bf16 pad -> 4-bank row skew

    int hop = blockIdx.y;
    const ushort_t* S  = (hop == 0) ? xb : (hop == 1) ? Y1b : Y2b;
    const ushort_t* WT = wbT + (size_t)hop * NC * NC;
    const float* B     = (hop == 0) ? b0 : (hop == 1) ? b1 : b2;
    const float* SV    = (hop == 0) ? nullptr : (hop == 1) ? s1 : s2;

    int tid = threadIdx.x;
    int m0 = blockIdx.x * 64;

    // stage S tile: thread t -> row t>>2, 32 bf16 at seg (t&3)*32
    {
        int r = tid >> 2;
        int seg = (tid & 3) * 32;
        int gr = m0 + r;
        uint4 z = {0, 0, 0, 0};
        uint4 v0 = z, v1 = z, v2 = z, v3 = z;
        if (gr < n) {
            const uint4* sp = (const uint4*)(S + (size_t)gr * NC + seg);
            v0 = sp[0]; v1 = sp[1]; v2 = sp[2]; v3 = sp[3];
        }
        uint4* dp = (uint4*)&ss[r][seg];
        dp[0] = v0; dp[1] = v1; dp[2] = v2; dp[3] = v3;
    }
    __syncthreads();

    int w  = tid >> 6;        // wave 0..3
    int l  = tid & 63;
    int lm = l & 15;
    int lh = l >> 4;          // 0..3

    // A-fragments for this wave's 16 rows, all 4 k-tiles
    short8v a[4];
    #pragma unroll
    for (int kk = 0; kk < 4; kk++)
        a[kk] = *(const short8v*)&ss[w * 16 + lm][kk * 32 + lh * 8];

    // per-lane row scales (4 output rows of this lane)
    float sc[4];
    #pragma unroll
    for (int j = 0; j < 4; j++) {
        int gr = m0 + w * 16 + lh * 4 + j;
        sc[j] = (SV && gr < n) ? SV[gr] : 1.0f;
    }

    #pragma unroll
    for (int nt = 0; nt < 8; nt++) {
        float4v c = {0.f, 0.f, 0.f, 0.f};
        const ushort_t* wp = WT + (size_t)(nt * 16 + lm) * NC + lh * 8;
        #pragma unroll
        for (int kk = 0; kk < 4; kk++) {
            short8v b = *(const short8v*)(wp + kk * 32);
            c = __builtin_amdgcn_mfma_f32_16x16x32_bf16(a[kk], b, c, 0, 0, 0);
        }
        int colg = nt * 16 + lm;
        float bb = B[colg];
        #pragma unroll
        for (int j = 0; j < 4; j++) {
            int gr = m0 + w * 16 + lh * 4 + j;
            if (gr < n)
                out[(size_t)gr * 384 + hop * NC + colg] = c[j] + sc[j] * bb;
        }
    }
}

// ---------------- launch ----------------

extern "C" void kernel_launch(void* const* d_in, const int* in_sizes, int n_in,
                              void* d_out, int out_size, void* d_ws, size_t ws_size,
                              hipStream_t stream) {
    const float* x  = (const float*)d_in[0];
    const float* ew = (const float*)d_in[1];
    const float* w0 = (const float*)d_in[2];
    const float* b0 = (const float*)d_in[3];
    const float* w1 = (const float*)d_in[4];
    const float* b1 = (const float*)d_in[5];
    const float* w2 = (const float*)d_in[6];
    const float* b2 = (const float*)d_in[7];
    const int* row  = (const int*)d_in[8];
    const int* col  = (const int*)d_in[9];
    float* out = (float*)d_out;

    const int N = in_sizes[0] / NC;  // 50000
    const int E = in_sizes[1];       // 600000

    char* ws = (char*)d_ws;
    size_t off = 0;
    auto alloc = [&](size_t bytes) {
        void* p = ws + off;
        off += (bytes + 255) & ~(size_t)255;
        return p;
    };
    ushort_t* xb   = (ushort_t*)alloc((size_t)N * NC * 2);
    ushort_t* Y1b  = (ushort_t*)alloc((size_t)N * NC * 2);
    ushort_t* Y2b  = (ushort_t*)alloc((size_t)N * NC * 2);
    ushort_t* wbT  = (ushort_t*)alloc((size_t)3 * NC * NC * 2);
    int* cnt       = (int*)alloc((size_t)N * 4);
    int* rowptr    = (int*)alloc((size_t)(N + 1) * 4);
    int* pos       = (int*)alloc((size_t)N * 4);
    float* s1      = (float*)alloc((size_t)N * 4);
    float* s2      = (float*)alloc((size_t)N * 4);
    int* ccol      = (int*)alloc((size_t)E * 4);
    float* cw      = (float*)alloc((size_t)E * 4);

    int nb = (N + SBLK - 1) / SBLK;
    int* bsum  = (int*)alloc((size_t)nb * 4);
    int* bbase = (int*)alloc((size_t)nb * 4);

    // converts + CSR build (zeroing via kernel — graph-safe, R7)
    zero_kernel<<<(N + 255) / 256, 256, 0, stream>>>(cnt, N);
    convert_x<<<((N * NC / 8) + 255) / 256, 256, 0, stream>>>(x, xb, N * NC / 8);
    convert_w<<<(3 * NC * NC + 255) / 256, 256, 0, stream>>>(w0, w1, w2, wbT);
    count_kernel<<<(E + 255) / 256, 256, 0, stream>>>(row, cnt, E);
    scan_partial<<<nb, SBLK, 0, stream>>>(cnt, bsum, N);
    scan_base<<<1, SBLK, 0, stream>>>(bsum, bbase, nb);
    scan_final<<<nb, SBLK, 0, stream>>>(cnt, bbase, rowptr, pos, N, E);
    scatter_kernel<<<(E + 255) / 256, 256, 0, stream>>>(row, col, ew, pos, ccol, cw, E);

    // Y1b = A@xb (+ s1 rowsums) ; s2 = A@s1 ; Y2b = A@Y1b
    int spmm_blocks = (N * 64 + 255) / 256;
    spmm_bf16<<<spmm_blocks, 256, 0, stream>>>(rowptr, ccol, cw, xb, Y1b, s1, N);
    s2_kernel<<<(N + 255) / 256, 256, 0, stream>>>(rowptr, ccol, cw, s1, s2, N);
    spmm_bf16<<<spmm_blocks, 256, 0, stream>>>(rowptr, ccol, cw, Y1b, Y2b, nullptr, N);

    // out = [xb@w0 + b0 | Y1b@w1 + s1*b1 | Y2b@w2 + s2*b2]  (MFMA)
    gemm3_mfma<<<dim3((N + 63) / 64, 3), 256, 0, stream>>>(
        xb, Y1b, Y2b, wbT, b0, b1, b2, s1, s2, out, N);
}